// Round 2
// baseline (524.211 us; speedup 1.0000x reference)
//
#include <hip/hip_runtime.h>
#include <hip/hip_bf16.h>

#define N_NODES 100000
#define N_EDGES 1000000
#define EMB 64
#define HID 64

// ---------------- workspace layout (bytes) ----------------
// [0)        deg_s   : N floats     (zeroed)
// [400k)     deg_r   : N floats     (zeroed)
// [800k)     agg     : N*64 floats  (zeroed)
// [26.4M)    out_acc : N floats     (zeroed)
// [26.8M)    h       : N*64 floats  (fully overwritten by k_gemm1)
// [52.4M)    z       : N floats     (fully overwritten by k_post)
// One memset covers [0, 26.8M).

__global__ void k_degrees(const int* __restrict__ senders,
                          const int* __restrict__ receivers,
                          float* __restrict__ deg_s, float* __restrict__ deg_r) {
    int i = blockIdx.x * blockDim.x + threadIdx.x;
    if (i < N_EDGES) {
        atomicAdd(&deg_s[senders[i]], 1.0f);
        atomicAdd(&deg_r[receivers[i]], 1.0f);
    }
}

// h[n][:] = (emb[node_ids[n]][:] @ W1) * rsqrt(max(deg_s[n],1))
__global__ void k_gemm1(const int* __restrict__ node_ids,
                        const float* __restrict__ emb,
                        const float* __restrict__ W1,
                        const float* __restrict__ deg_s,
                        float* __restrict__ h) {
    __shared__ float W1s[64 * 64];
    int t = threadIdx.x;
    // stage W1 into LDS (16 KB)
    for (int i = t; i < 64 * 64; i += blockDim.x) W1s[i] = W1[i];
    __syncthreads();

    int n = blockIdx.x * blockDim.x + t;
    if (n >= N_NODES) return;
    int nid = node_ids[n];

    // load emb row (64 f32 = 256 B) into registers
    float e[64];
    const float4* erow = (const float4*)(emb + (size_t)nid * 64);
#pragma unroll
    for (int q = 0; q < 16; ++q) {
        float4 u = erow[q];
        e[q * 4 + 0] = u.x; e[q * 4 + 1] = u.y;
        e[q * 4 + 2] = u.z; e[q * 4 + 3] = u.w;
    }

    float scale = rsqrtf(fmaxf(deg_s[n], 1.0f));
    float* hrow = h + (size_t)n * 64;

#pragma unroll 4
    for (int j0 = 0; j0 < 64; j0 += 4) {
        float a0 = 0.f, a1 = 0.f, a2 = 0.f, a3 = 0.f;
#pragma unroll
        for (int k = 0; k < 64; ++k) {
            const float4 w = *(const float4*)&W1s[k * 64 + j0];  // wave-broadcast read
            a0 += e[k] * w.x;
            a1 += e[k] * w.y;
            a2 += e[k] * w.z;
            a3 += e[k] * w.w;
        }
        float4 o;
        o.x = a0 * scale; o.y = a1 * scale; o.z = a2 * scale; o.w = a3 * scale;
        *(float4*)&hrow[j0] = o;
    }
}

// agg[r][:] += h[s][:]  for each edge — wave per edge, lane = feature
__global__ void k_scatter64(const int* __restrict__ senders,
                            const int* __restrict__ receivers,
                            const float* __restrict__ h,
                            float* __restrict__ agg) {
    int gtid = blockIdx.x * blockDim.x + threadIdx.x;
    int wid  = gtid >> 6;
    int lane = threadIdx.x & 63;
    int nwaves = (gridDim.x * blockDim.x) >> 6;
    for (int e = wid; e < N_EDGES; e += nwaves) {
        int s = senders[e];
        int r = receivers[e];
        float v = h[(size_t)s * 64 + lane];
        atomicAdd(&agg[(size_t)r * 64 + lane], v);
    }
}

// z[n] = leaky_relu(agg[n][:] * rsqrt(max(deg_r[n],1))) . W2 + b2 — wave per node
__global__ void k_post(const float* __restrict__ agg,
                       const float* __restrict__ deg_r,
                       const float* __restrict__ W2,
                       const float* __restrict__ b2,
                       float* __restrict__ z) {
    int gtid = blockIdx.x * blockDim.x + threadIdx.x;
    int n    = gtid >> 6;
    int lane = threadIdx.x & 63;
    if (n >= N_NODES) return;
    float scale = rsqrtf(fmaxf(deg_r[n], 1.0f));
    float x = agg[(size_t)n * 64 + lane] * scale;
    x = (x > 0.f) ? x : 0.01f * x;
    float p = x * W2[lane];
#pragma unroll
    for (int off = 32; off > 0; off >>= 1) p += __shfl_xor(p, off, 64);
    if (lane == 0) z[n] = p + b2[0];
}

// out_acc[r] += z[s] for each edge
__global__ void k_scatter1(const int* __restrict__ senders,
                           const int* __restrict__ receivers,
                           const float* __restrict__ z,
                           float* __restrict__ out_acc) {
    int i = blockIdx.x * blockDim.x + threadIdx.x;
    if (i < N_EDGES) {
        atomicAdd(&out_acc[receivers[i]], z[senders[i]]);
    }
}

__global__ void k_sigmoid(const float* __restrict__ out_acc,
                          float* __restrict__ out) {
    int i = blockIdx.x * blockDim.x + threadIdx.x;
    if (i < N_NODES) {
        float v = out_acc[i];
        out[i] = 1.0f / (1.0f + expf(-v));
    }
}

extern "C" void kernel_launch(void* const* d_in, const int* in_sizes, int n_in,
                              void* d_out, int out_size, void* d_ws, size_t ws_size,
                              hipStream_t stream) {
    const int* node_ids   = (const int*)d_in[0];
    const int* senders    = (const int*)d_in[1];
    const int* receivers  = (const int*)d_in[2];
    const float* emb      = (const float*)d_in[3];
    const float* W1       = (const float*)d_in[4];
    const float* W2       = (const float*)d_in[5];
    const float* b2       = (const float*)d_in[6];
    float* out            = (float*)d_out;

    char* ws = (char*)d_ws;
    const size_t NB = (size_t)N_NODES * 4;          // 400,000 B
    float* deg_s   = (float*)(ws);
    float* deg_r   = (float*)(ws + NB);
    float* agg     = (float*)(ws + 2 * NB);                       // N*64 f32
    float* out_acc = (float*)(ws + 2 * NB + (size_t)N_NODES * 64 * 4);
    float* h       = (float*)(ws + 3 * NB + (size_t)N_NODES * 64 * 4);
    float* z       = (float*)(ws + 3 * NB + (size_t)N_NODES * 128 * 4);

    // zero deg_s, deg_r, agg, out_acc in one shot (contiguous prefix)
    hipMemsetAsync(ws, 0, 3 * NB + (size_t)N_NODES * 64 * 4, stream);

    const int B = 256;
    k_degrees<<<(N_EDGES + B - 1) / B, B, 0, stream>>>(senders, receivers, deg_s, deg_r);
    k_gemm1<<<(N_NODES + B - 1) / B, B, 0, stream>>>(node_ids, emb, W1, deg_s, h);
    k_scatter64<<<4096, B, 0, stream>>>(senders, receivers, h, agg);
    k_post<<<(N_NODES * 64 + B - 1) / B, B, 0, stream>>>(agg, deg_r, W2, b2, z);
    k_scatter1<<<(N_EDGES + B - 1) / B, B, 0, stream>>>(senders, receivers, z, out_acc);
    k_sigmoid<<<(N_NODES + B - 1) / B, B, 0, stream>>>(out_acc, out);
}

// Round 3
// 363.479 us; speedup vs baseline: 1.4422x; 1.4422x over previous
//
#include <hip/hip_runtime.h>
#include <hip/hip_bf16.h>

#define N_NODES 100000
#define N_EDGES 1000000
#define EMB 64
#define HID 64
#define SCAN_B 256
#define N_BLOCKS_SCAN ((N_NODES + SCAN_B - 1) / SCAN_B)   // 391

// ---------------- workspace layout (bytes) ----------------
// cnt_s     [0        ..   400,000)  int   (zeroed)
// cnt_r     [400,000  ..   800,000)  int   (zeroed)
// row_start [800,000  .. 1,200,016)  int[N+1]
// cursor    [1,200,016.. 1,600,016)  int
// blockSums [1,600,016.. 1,601,584)  int[391]
// blockOffs [1,601,584.. 1,603,152)  int[391]
// col       [1,603,152.. 5,603,152)  int[E]
// h         [5,603,152..31,203,152)  float[N*64]
// z         [31,203,152..31,603,152) float[N]
// memset covers [0, 800,000) only.

__global__ void k_count(const int* __restrict__ senders,
                        const int* __restrict__ receivers,
                        int* __restrict__ cnt_s, int* __restrict__ cnt_r) {
    int i = blockIdx.x * blockDim.x + threadIdx.x;
    if (i < N_EDGES) {
        atomicAdd(&cnt_s[senders[i]], 1);
        atomicAdd(&cnt_r[receivers[i]], 1);
    }
}

// ---- 3-pass exclusive scan of cnt_r -> row_start (and cursor copy) ----
__global__ void k_scanA(const int* __restrict__ cnt_r, int* __restrict__ blockSums) {
    __shared__ int s[SCAN_B];
    int t = threadIdx.x;
    int idx = blockIdx.x * SCAN_B + t;
    int v = (idx < N_NODES) ? cnt_r[idx] : 0;
    s[t] = v;
    __syncthreads();
    for (int off = 1; off < SCAN_B; off <<= 1) {
        int x = (t >= off) ? s[t - off] : 0;
        __syncthreads();
        s[t] += x;
        __syncthreads();
    }
    if (t == SCAN_B - 1) blockSums[blockIdx.x] = s[t];
}

__global__ void k_scanB(const int* __restrict__ blockSums, int* __restrict__ blockOffs) {
    __shared__ int s[512];
    int t = threadIdx.x;   // 512 threads, 1 block
    int v = (t < N_BLOCKS_SCAN) ? blockSums[t] : 0;
    s[t] = v;
    __syncthreads();
    for (int off = 1; off < 512; off <<= 1) {
        int x = (t >= off) ? s[t - off] : 0;
        __syncthreads();
        s[t] += x;
        __syncthreads();
    }
    if (t < N_BLOCKS_SCAN) blockOffs[t] = s[t] - v;   // exclusive
}

__global__ void k_scanC(const int* __restrict__ cnt_r, const int* __restrict__ blockOffs,
                        int* __restrict__ row_start, int* __restrict__ cursor) {
    __shared__ int s[SCAN_B];
    int t = threadIdx.x;
    int idx = blockIdx.x * SCAN_B + t;
    int v = (idx < N_NODES) ? cnt_r[idx] : 0;
    s[t] = v;
    __syncthreads();
    for (int off = 1; off < SCAN_B; off <<= 1) {
        int x = (t >= off) ? s[t - off] : 0;
        __syncthreads();
        s[t] += x;
        __syncthreads();
    }
    if (idx < N_NODES) {
        int row = blockOffs[blockIdx.x] + s[t] - v;   // exclusive prefix
        row_start[idx] = row;
        cursor[idx] = row;
    }
    if (blockIdx.x == 0 && t == 0) row_start[N_NODES] = N_EDGES;
}

__global__ void k_fill(const int* __restrict__ senders, const int* __restrict__ receivers,
                       int* __restrict__ cursor, int* __restrict__ col) {
    int i = blockIdx.x * blockDim.x + threadIdx.x;
    if (i < N_EDGES) {
        int r = receivers[i];
        int pos = atomicAdd(&cursor[r], 1);
        col[pos] = senders[i];
    }
}

// h[n][:] = (emb[n][:] @ W1) * rsqrt(max(send_deg[n],1))   (node_ids == arange)
__global__ void k_gemm1(const int* __restrict__ node_ids,
                        const float* __restrict__ emb,
                        const float* __restrict__ W1,
                        const int* __restrict__ cnt_s,
                        float* __restrict__ h) {
    __shared__ float W1s[64 * 64];
    int t = threadIdx.x;
    for (int i = t; i < 64 * 64; i += blockDim.x) W1s[i] = W1[i];
    __syncthreads();

    int n = blockIdx.x * blockDim.x + t;
    if (n >= N_NODES) return;
    int nid = node_ids[n];

    float e[64];
    const float4* erow = (const float4*)(emb + (size_t)nid * 64);
#pragma unroll
    for (int q = 0; q < 16; ++q) {
        float4 u = erow[q];
        e[q * 4 + 0] = u.x; e[q * 4 + 1] = u.y;
        e[q * 4 + 2] = u.z; e[q * 4 + 3] = u.w;
    }

    float scale = rsqrtf(fmaxf((float)cnt_s[n], 1.0f));
    float* hrow = h + (size_t)n * 64;

#pragma unroll 4
    for (int j0 = 0; j0 < 64; j0 += 4) {
        float a0 = 0.f, a1 = 0.f, a2 = 0.f, a3 = 0.f;
#pragma unroll
        for (int k = 0; k < 64; ++k) {
            const float4 w = *(const float4*)&W1s[k * 64 + j0];
            a0 += e[k] * w.x;
            a1 += e[k] * w.y;
            a2 += e[k] * w.z;
            a3 += e[k] * w.w;
        }
        float4 o;
        o.x = a0 * scale; o.y = a1 * scale; o.z = a2 * scale; o.w = a3 * scale;
        *(float4*)&hrow[j0] = o;
    }
}

// wave per node: acc[lane] = sum over in-edges of h[s][lane];
// then recv-norm + leaky_relu + dot W2 + b2 -> z[n]
__global__ void k_agg_post(const int* __restrict__ row_start,
                           const int* __restrict__ col,
                           const float* __restrict__ h,
                           const float* __restrict__ W2,
                           const float* __restrict__ b2,
                           float* __restrict__ z) {
    int gtid = blockIdx.x * blockDim.x + threadIdx.x;
    int n    = gtid >> 6;
    int lane = threadIdx.x & 63;
    if (n >= N_NODES) return;
    int start = row_start[n];
    int end   = row_start[n + 1];
    float acc = 0.f;
    int i = start;
    // 2-way unroll to keep two gathers in flight
    for (; i + 1 < end; i += 2) {
        int s0 = col[i];
        int s1 = col[i + 1];
        float v0 = h[(size_t)s0 * 64 + lane];
        float v1 = h[(size_t)s1 * 64 + lane];
        acc += v0 + v1;
    }
    if (i < end) {
        int s0 = col[i];
        acc += h[(size_t)s0 * 64 + lane];
    }
    float deg = (float)(end - start);
    float x = acc * rsqrtf(fmaxf(deg, 1.0f));
    x = (x > 0.f) ? x : 0.01f * x;
    float p = x * W2[lane];
#pragma unroll
    for (int off = 32; off > 0; off >>= 1) p += __shfl_xor(p, off, 64);
    if (lane == 0) z[n] = p + b2[0];
}

// thread per node: out[n] = sigmoid( sum over in-edges z[s] )
__global__ void k_agg2_sigmoid(const int* __restrict__ row_start,
                               const int* __restrict__ col,
                               const float* __restrict__ z,
                               float* __restrict__ out) {
    int n = blockIdx.x * blockDim.x + threadIdx.x;
    if (n >= N_NODES) return;
    int start = row_start[n];
    int end   = row_start[n + 1];
    float acc = 0.f;
    for (int i = start; i < end; ++i) acc += z[col[i]];
    out[n] = 1.0f / (1.0f + expf(-acc));
}

extern "C" void kernel_launch(void* const* d_in, const int* in_sizes, int n_in,
                              void* d_out, int out_size, void* d_ws, size_t ws_size,
                              hipStream_t stream) {
    const int* node_ids   = (const int*)d_in[0];
    const int* senders    = (const int*)d_in[1];
    const int* receivers  = (const int*)d_in[2];
    const float* emb      = (const float*)d_in[3];
    const float* W1       = (const float*)d_in[4];
    const float* W2       = (const float*)d_in[5];
    const float* b2       = (const float*)d_in[6];
    float* out            = (float*)d_out;

    char* ws = (char*)d_ws;
    int*   cnt_s     = (int*)(ws);
    int*   cnt_r     = (int*)(ws + 400000);
    int*   row_start = (int*)(ws + 800000);
    int*   cursor    = (int*)(ws + 1200016);
    int*   blockSums = (int*)(ws + 1600016);
    int*   blockOffs = (int*)(ws + 1601584);
    int*   col       = (int*)(ws + 1603152);
    float* h         = (float*)(ws + 5603152);
    float* z         = (float*)(ws + 31203152);

    hipMemsetAsync(ws, 0, 800000, stream);   // cnt_s + cnt_r

    const int B = 256;
    k_count<<<(N_EDGES + B - 1) / B, B, 0, stream>>>(senders, receivers, cnt_s, cnt_r);
    k_scanA<<<N_BLOCKS_SCAN, SCAN_B, 0, stream>>>(cnt_r, blockSums);
    k_scanB<<<1, 512, 0, stream>>>(blockSums, blockOffs);
    k_scanC<<<N_BLOCKS_SCAN, SCAN_B, 0, stream>>>(cnt_r, blockOffs, row_start, cursor);
    k_fill<<<(N_EDGES + B - 1) / B, B, 0, stream>>>(senders, receivers, cursor, col);
    k_gemm1<<<(N_NODES + B - 1) / B, B, 0, stream>>>(node_ids, emb, W1, cnt_s, h);
    k_agg_post<<<(N_NODES * 64 + B - 1) / B, B, 0, stream>>>(row_start, col, h, W2, b2, z);
    k_agg2_sigmoid<<<(N_NODES + B - 1) / B, B, 0, stream>>>(row_start, col, z, out);
}